// Round 7
// baseline (3212.999 us; speedup 1.0000x reference)
//
#include <hip/hip_runtime.h>
#include <hip/hip_bf16.h>
#include <cmath>

// EncoderDecoder: S=49,B=64,DENC=512,DD=1800,DE=512,V=10000,T=20
// Round 7: ws-adaptive split-K (z derived from ws_size, no binary gates),
// mfma_gemm4 = JIT A-loads + depth-1 W prefetch, Q z=25.

namespace {

constexpr int S = 49, B = 64, DENC = 512, DD = 1800, DE = 512, V = 10000, T = 20;
constexpr int KC = DD + DE + DENC;   // 2824
constexpr int G4 = 4 * DD;           // 7200
constexpr int KCP = 2848;            // KC padded to %32 (= KC-8+31+1 bound exactly)
constexpr int DDP = 1824;            // DD padded to %32

typedef __attribute__((ext_vector_type(8))) short short8;
typedef __attribute__((ext_vector_type(4))) float f32x4;

__device__ inline float sigf(float x) { return 1.f / (1.f + expf(-x)); }

__device__ inline ushort f2bf_rne(float x) {
  unsigned u = __float_as_uint(x);
  unsigned r = (u + 0x7FFFu + ((u >> 16) & 1u)) >> 16;
  return (ushort)r;
}
__device__ inline void split1(float x, ushort& h, ushort& l) {
  h = f2bf_rne(x);
  float hf = __uint_as_float(((unsigned)h) << 16);
  l = f2bf_rne(x - hf);
}
__device__ inline void split8(float4 a, float4 b, short8& hi, short8& lo) {
  float v[8] = {a.x, a.y, a.z, a.w, b.x, b.y, b.z, b.w};
#pragma unroll
  for (int i = 0; i < 8; ++i) {
    ushort h, l; split1(v[i], h, l);
    hi[i] = (short)h; lo[i] = (short)l;
  }
}

// ---------------- h_avg = mean_s h[s,b,:] ----------------
__global__ __launch_bounds__(256) void hmean_kernel(const float* __restrict__ h,
                                                    float* __restrict__ h_avg) {
  int idx = blockIdx.x * 256 + threadIdx.x;
  if (idx >= B * DENC) return;
  float s = 0.f;
  for (int si = 0; si < S; ++si) s += h[(size_t)si * B * DENC + idx];
  h_avg[idx] = s * (1.0f / (float)S);
}

// ---------------- MFMA bf16x3 GEMM v4: JIT A-loads, depth-1 W prefetch ----
// C[m,n] = sum_k A[m,k]*W[n,k]. A pre-split bf16 hi/lo, zero-padded to ldap
// (>= K-8+32, %32). W fp32 rows [Wa[n][0:Ka] | Wb[n][...]], Ka%8==0, split
// in-register. Wave: 32 n-cols (2 tiles), 64 m-rows. kchunk%8==0;
// grid.z*kchunk >= K. Writes fp32 partials P[z][M][N]. M%64==0.
__global__ __launch_bounds__(256) void mfma_gemm4(
    const ushort* __restrict__ Ahi, const ushort* __restrict__ Alo, int ldap,
    const float* __restrict__ Wa, int ldwa, int Ka,
    const float* __restrict__ Wb, int ldwb,
    float* __restrict__ P, int M, int N, int K, int kchunk) {
  const int lane = threadIdx.x & 63;
  const int wv = threadIdx.x >> 6;
  const int nbase = blockIdx.x * 128 + wv * 32;
  const int bm = blockIdx.y * 64;
  const int z = blockIdx.z;
  const int row = lane & 15;
  const int kg = (lane >> 4) * 8;
  const int k_begin = z * kchunk;
  const int k_end = min(K, k_begin + kchunk);

  const int n0 = nbase + row, n1 = n0 + 16;
  const int nc0 = (n0 < N) ? n0 : (N - 1);
  const int nc1 = (n1 < N) ? n1 : (N - 1);

  const ushort* pa_hi = Ahi + (size_t)(bm + row) * ldap + kg;
  const ushort* pa_lo = Alo + (size_t)(bm + row) * ldap + kg;

  f32x4 acc[2][4] = {};

  auto wptr = [&](int nc, int k) -> const float* {
    return (k < Ka) ? (Wa + (size_t)nc * ldwa + k)
                    : (Wb + (size_t)nc * ldwb + (k - Ka));
  };
  auto loadW2 = [&](int kk, float4* w) {
    const float* p0 = wptr(nc0, kk + kg);
    const float* p1 = wptr(nc1, kk + kg);
    w[0] = *(const float4*)p0; w[1] = *(const float4*)(p0 + 4);
    w[2] = *(const float4*)p1; w[3] = *(const float4*)(p1 + 4);
  };
  auto loadA = [&](int kk, short8* ah, short8* al) {
#pragma unroll
    for (int ms = 0; ms < 4; ++ms) {
      ah[ms] = *(const short8*)(pa_hi + (size_t)(ms * 16) * ldap + kk);
      al[ms] = *(const short8*)(pa_lo + (size_t)(ms * 16) * ldap + kk);
    }
  };

  const int nfull = (k_end > k_begin) ? ((k_end - k_begin) >> 5) : 0;
  float4 cw[4];
  if (nfull) loadW2(k_begin, cw);
  for (int it = 0; it < nfull; ++it) {
    const int kk = k_begin + it * 32;
    // JIT A loads (L2-hot; latency hidden by the split VALU below)
    short8 ah[4], al[4];
    loadA(kk, ah, al);
    // depth-1 W prefetch (HBM)
    const bool more = (it + 1 < nfull);
    float4 nw[4];
    if (more) loadW2(kk + 32, nw);
    short8 wh0, wl0, wh1, wl1;
    split8(cw[0], cw[1], wh0, wl0);
    split8(cw[2], cw[3], wh1, wl1);
#pragma unroll
    for (int ms = 0; ms < 4; ++ms) {
      acc[0][ms] = __builtin_amdgcn_mfma_f32_16x16x32_bf16(ah[ms], wh0, acc[0][ms], 0, 0, 0);
      acc[0][ms] = __builtin_amdgcn_mfma_f32_16x16x32_bf16(al[ms], wh0, acc[0][ms], 0, 0, 0);
      acc[0][ms] = __builtin_amdgcn_mfma_f32_16x16x32_bf16(ah[ms], wl0, acc[0][ms], 0, 0, 0);
      acc[1][ms] = __builtin_amdgcn_mfma_f32_16x16x32_bf16(ah[ms], wh1, acc[1][ms], 0, 0, 0);
      acc[1][ms] = __builtin_amdgcn_mfma_f32_16x16x32_bf16(al[ms], wh1, acc[1][ms], 0, 0, 0);
      acc[1][ms] = __builtin_amdgcn_mfma_f32_16x16x32_bf16(ah[ms], wl1, acc[1][ms], 0, 0, 0);
    }
    if (more) {
#pragma unroll
      for (int q = 0; q < 4; ++q) cw[q] = nw[q];
    }
  }
  // tail: rem in {8,16,24}; A zero-padding nulls k >= K (max idx K-8+31 < ldap)
  const int ktail = k_begin + nfull * 32;
  if (ktail < k_end) {
    int rem = k_end - ktail;
    short8 wh0 = {}, wl0 = {}, wh1 = {}, wl1 = {};
    if (kg < rem) {
      float4 w[4];
      loadW2(ktail, w);
      split8(w[0], w[1], wh0, wl0);
      split8(w[2], w[3], wh1, wl1);
    }
    short8 tah[4], tal[4];
    loadA(ktail, tah, tal);
#pragma unroll
    for (int ms = 0; ms < 4; ++ms) {
      acc[0][ms] = __builtin_amdgcn_mfma_f32_16x16x32_bf16(tah[ms], wh0, acc[0][ms], 0, 0, 0);
      acc[0][ms] = __builtin_amdgcn_mfma_f32_16x16x32_bf16(tal[ms], wh0, acc[0][ms], 0, 0, 0);
      acc[0][ms] = __builtin_amdgcn_mfma_f32_16x16x32_bf16(tah[ms], wl0, acc[0][ms], 0, 0, 0);
      acc[1][ms] = __builtin_amdgcn_mfma_f32_16x16x32_bf16(tah[ms], wh1, acc[1][ms], 0, 0, 0);
      acc[1][ms] = __builtin_amdgcn_mfma_f32_16x16x32_bf16(tal[ms], wh1, acc[1][ms], 0, 0, 0);
      acc[1][ms] = __builtin_amdgcn_mfma_f32_16x16x32_bf16(tah[ms], wl1, acc[1][ms], 0, 0, 0);
    }
  }

  float* Pz = P + (size_t)z * ((size_t)M * N);
#pragma unroll
  for (int j = 0; j < 2; ++j) {
    int n = nbase + j * 16 + row;
    if (n >= N) continue;
#pragma unroll
    for (int ms = 0; ms < 4; ++ms) {
      int r0 = bm + ms * 16 + (lane >> 4) * 4;
#pragma unroll
      for (int r = 0; r < 4; ++r) {
        Pz[(size_t)(r0 + r) * N + n] = acc[j][ms][r];
      }
    }
  }
}

// ---------------- reduce over split-K partials (+bias, +relu) ----------------
template <int ACT>
__global__ __launch_bounds__(256) void reduce_k(const float* __restrict__ P, int nz,
                                                int total4, size_t MN, int N,
                                                const float* __restrict__ bias,
                                                float* __restrict__ C) {
  int i4 = blockIdx.x * 256 + threadIdx.x;
  if (i4 >= total4) return;
  size_t idx = (size_t)i4 * 4;
  float4 s = *(const float4*)(P + idx);
  for (int zz = 1; zz < nz; ++zz) {
    float4 t = *(const float4*)(P + (size_t)zz * MN + idx);
    s.x += t.x; s.y += t.y; s.z += t.z; s.w += t.w;
  }
  if (bias) {
    int nn = (int)(idx % (size_t)N);
    s.x += bias[nn]; s.y += bias[nn + 1]; s.z += bias[nn + 2]; s.w += bias[nn + 3];
  }
  if (ACT == 1) {
    s.x = fmaxf(s.x, 0.f); s.y = fmaxf(s.y, 0.f);
    s.z = fmaxf(s.z, 0.f); s.w = fmaxf(s.w, 0.f);
  }
  *(float4*)(C + idx) = s;
}

// ---------------- split fp32 rows -> bf16 hi/lo with zero pad ----------------
__global__ __launch_bounds__(256) void split_pad(const float* __restrict__ src, int K,
                                                 int KP, int rows,
                                                 ushort* __restrict__ hi,
                                                 ushort* __restrict__ lo) {
  int idx = blockIdx.x * 256 + threadIdx.x;
  if (idx >= rows * KP) return;
  int r = idx / KP, k = idx % KP;
  ushort h = 0, l = 0;
  if (k < K) split1(src[(size_t)r * K + k], h, l);
  hi[idx] = h; lo[idx] = l;
}

// ---------------- u[s,b] = relu(Q[b,:] + Hproj[s,b,:]) . w2 + b2 ----------------
__global__ __launch_bounds__(256) void attn_u_kernel(const float* __restrict__ Q,
                                                     const float* __restrict__ Hproj,
                                                     const float* __restrict__ w2,
                                                     const float* __restrict__ b2,
                                                     float* __restrict__ u) {
  int s = blockIdx.x, b = blockIdx.y;
  const float4* q4 = (const float4*)(Q + (size_t)b * DD);
  const float4* h4 = (const float4*)(Hproj + ((size_t)s * B + b) * DD);
  const float4* w4 = (const float4*)w2;
  float acc = 0.f;
  for (int i = threadIdx.x; i < DD / 4; i += 256) {
    float4 q = q4[i], hh = h4[i], w = w4[i];
    acc += fmaxf(q.x + hh.x, 0.f) * w.x + fmaxf(q.y + hh.y, 0.f) * w.y +
           fmaxf(q.z + hh.z, 0.f) * w.z + fmaxf(q.w + hh.w, 0.f) * w.w;
  }
  for (int off = 32; off; off >>= 1) acc += __shfl_xor(acc, off);
  __shared__ float red[4];
  if ((threadIdx.x & 63) == 0) red[threadIdx.x >> 6] = acc;
  __syncthreads();
  if (threadIdx.x == 0) u[s * B + b] = red[0] + red[1] + red[2] + red[3] + b2[0];
}

// ---------------- per-(b,slice): softmax, beta; slice of ctx + packing ----------------
__global__ __launch_bounds__(256) void softmax_ctx_pack(
    const float* __restrict__ u, const float* __restrict__ h,
    const float* __restrict__ ht, const float* __restrict__ beta_w,
    const float* __restrict__ beta_b, const float* __restrict__ emb,
    const int* __restrict__ Et, const int* __restrict__ prev_tok,
    ushort* __restrict__ xcat_hi, ushort* __restrict__ xcat_lo,
    ushort* __restrict__ cat2_hi, ushort* __restrict__ cat2_lo) {
  int b = blockIdx.x, slice = blockIdx.y, tid = threadIdx.x;
  __shared__ float a_sh[S];
  __shared__ float red[4];
  float uv = (tid < S) ? u[tid * B + b] : -INFINITY;
  float m = uv;
  for (int off = 32; off; off >>= 1) m = fmaxf(m, __shfl_xor(m, off));
  if ((tid & 63) == 0) red[tid >> 6] = m;
  __syncthreads();
  m = fmaxf(fmaxf(red[0], red[1]), fmaxf(red[2], red[3]));
  float e = (tid < S) ? expf(uv - m) : 0.f;
  float ssum = e;
  for (int off = 32; off; off >>= 1) ssum += __shfl_xor(ssum, off);
  __syncthreads();
  if ((tid & 63) == 0) red[tid >> 6] = ssum;
  __syncthreads();
  ssum = red[0] + red[1] + red[2] + red[3];
  if (tid < S) a_sh[tid] = e / ssum;
  float acc = 0.f;
  {
    const float4* h4 = (const float4*)(ht + (size_t)b * DD);
    const float4* w4 = (const float4*)beta_w;
    for (int i = tid; i < DD / 4; i += 256) {
      float4 x = h4[i], w = w4[i];
      acc += x.x * w.x + x.y * w.y + x.z * w.z + x.w * w.w;
    }
  }
  for (int off = 32; off; off >>= 1) acc += __shfl_xor(acc, off);
  __syncthreads();
  if ((tid & 63) == 0) red[tid >> 6] = acc;
  __syncthreads();
  float beta = sigf(red[0] + red[1] + red[2] + red[3] + beta_b[0]);

  const size_t xb = (size_t)b * KCP;
  for (int e0 = slice * 128 + tid; e0 < slice * 128 + 128; e0 += 256) {
    float c = 0.f;
    for (int si = 0; si < S; ++si) c += a_sh[si] * h[((size_t)si * B + b) * DENC + e0];
    c *= beta;
    ushort hh, ll; split1(c, hh, ll);
    xcat_hi[xb + DE + e0] = hh;      xcat_lo[xb + DE + e0] = ll;
    cat2_hi[xb + DD + DE + e0] = hh; cat2_lo[xb + DD + DE + e0] = ll;
  }
  int et = Et[b];
  int pt = prev_tok[b];
  for (int e0 = slice * 128 + tid; e0 < slice * 128 + 128; e0 += 256) {
    ushort hh, ll;
    split1(emb[(size_t)et * DE + e0], hh, ll);
    xcat_hi[xb + e0] = hh; xcat_lo[xb + e0] = ll;
    split1(emb[(size_t)pt * DE + e0], hh, ll);
    cat2_hi[xb + DD + e0] = hh; cat2_lo[xb + DD + e0] = ll;
  }
  for (int j = slice * 450 + tid; j < slice * 450 + 450; j += 256) {
    ushort hh, ll; split1(ht[(size_t)b * DD + j], hh, ll);
    xcat_hi[xb + DE + DENC + j] = hh; xcat_lo[xb + DE + DENC + j] = ll;
  }
  if (slice == 3 && tid < KCP - KC) {
    xcat_hi[xb + KC + tid] = 0; xcat_lo[xb + KC + tid] = 0;
    cat2_hi[xb + KC + tid] = 0; cat2_lo[xb + KC + tid] = 0;
  }
}

// ---------------- LSTM: reduce gates partials + update + bf16 splits ----------------
__global__ __launch_bounds__(256) void lstm_fused(
    const float* __restrict__ P, int nz, const float* __restrict__ b_ih,
    const float* __restrict__ b_hh, float* __restrict__ ct, float* __restrict__ ht,
    ushort* __restrict__ cat2_hi, ushort* __restrict__ cat2_lo,
    ushort* __restrict__ ht_hi, ushort* __restrict__ ht_lo) {
  int idx = blockIdx.x * 256 + threadIdx.x;
  if (idx >= B * DD) return;
  int b = idx / DD, d = idx % DD;
  const size_t MN = (size_t)B * G4;
  float g0 = 0.f, g1 = 0.f, g2 = 0.f, g3 = 0.f;
  for (int zz = 0; zz < nz; ++zz) {
    const float* g = P + (size_t)zz * MN + (size_t)b * G4;
    g0 += g[d]; g1 += g[DD + d]; g2 += g[2 * DD + d]; g3 += g[3 * DD + d];
  }
  g0 += b_ih[d] + b_hh[d];
  g1 += b_ih[DD + d] + b_hh[DD + d];
  g2 += b_ih[2 * DD + d] + b_hh[2 * DD + d];
  g3 += b_ih[3 * DD + d] + b_hh[3 * DD + d];
  float c = sigf(g1) * ct[idx] + sigf(g0) * tanhf(g2);
  float hn = sigf(g3) * tanhf(c);
  ct[idx] = c;
  ht[idx] = hn;
  ushort hh, ll; split1(hn, hh, ll);
  cat2_hi[(size_t)b * KCP + d] = hh; cat2_lo[(size_t)b * KCP + d] = ll;
  ht_hi[(size_t)b * DDP + d] = hh;   ht_lo[(size_t)b * DDP + d] = ll;
  if (d < DDP - DD) {
    ht_hi[(size_t)b * DDP + DD + d] = 0; ht_lo[(size_t)b * DDP + DD + d] = 0;
  }
}

// ---------------- per-b argmax over V ----------------
__global__ __launch_bounds__(256) void argmax_kernel(const float* __restrict__ logits,
                                                     int* __restrict__ tok) {
  int b = blockIdx.x;
  const float* row = logits + (size_t)b * V;
  float best = -INFINITY;
  int bi = 0x7fffffff;
  for (int v = threadIdx.x; v < V; v += 256) {
    float x = row[v];
    if (x > best) { best = x; bi = v; }
  }
  for (int off = 32; off; off >>= 1) {
    float ov = __shfl_xor(best, off);
    int oi = __shfl_xor(bi, off);
    if (ov > best || (ov == best && oi < bi)) { best = ov; bi = oi; }
  }
  __shared__ float bv[4];
  __shared__ int bix[4];
  if ((threadIdx.x & 63) == 0) { bv[threadIdx.x >> 6] = best; bix[threadIdx.x >> 6] = bi; }
  __syncthreads();
  if (threadIdx.x == 0) {
    for (int w = 1; w < 4; ++w)
      if (bv[w] > best || (bv[w] == best && bix[w] < bi)) { best = bv[w]; bi = bix[w]; }
    tok[b] = bi;
  }
}

__global__ void zero_tok(int* tok) { if (threadIdx.x < B) tok[threadIdx.x] = 0; }

// ws layout: fixed fp32 region, then ushort region, then PBUF (extensible).
constexpr size_t OFF_HAVG  = 0;                       // 64*512
constexpr size_t OFF_TMP   = OFF_HAVG + 32768;        // 64*1800
constexpr size_t OFF_HT    = OFF_TMP + 115200;
constexpr size_t OFF_CT    = OFF_HT + 115200;
constexpr size_t OFF_HPROJ = OFF_CT + 115200;         // 3136*1800
constexpr size_t OFF_Q     = OFF_HPROJ + 5644800;
constexpr size_t OFF_U     = OFF_Q + 115200;
constexpr size_t OFF_TOK   = OFF_U + 3200;
constexpr size_t OFF_USH   = OFF_TOK + 128;           // ushort area (float offset)

// ushort offsets within ushort area
constexpr size_t U_HT_HI   = 0;                            // 64*1824
constexpr size_t U_HT_LO   = U_HT_HI + (size_t)B * DDP;
constexpr size_t U_XC_HI   = U_HT_LO + (size_t)B * DDP;    // 64*2848
constexpr size_t U_XC_LO   = U_XC_HI + (size_t)B * KCP;
constexpr size_t U_C2_HI   = U_XC_LO + (size_t)B * KCP;
constexpr size_t U_C2_LO   = U_C2_HI + (size_t)B * KCP;
constexpr size_t U_H_HI    = U_C2_LO + (size_t)B * KCP;    // 3136*512
constexpr size_t U_H_LO    = U_H_HI + (size_t)(S * B) * DENC;
constexpr size_t U_END     = U_H_LO + (size_t)(S * B) * DENC;  // 4,173,824

constexpr size_t OFF_PBUF  = OFF_USH + U_END / 2;     // 8,228,608 floats

}  // namespace

extern "C" void kernel_launch(void* const* d_in, const int* in_sizes, int n_in,
                              void* d_out, int out_size, void* d_ws, size_t ws_size,
                              hipStream_t stream) {
  const float* h       = (const float*)d_in[0];
  const int*   E       = (const int*)d_in[1];
  const float* emb     = (const float*)d_in[2];
  const float* attn_W1 = (const float*)d_in[3];
  const float* attn_b1 = (const float*)d_in[4];
  const float* attn_w2 = (const float*)d_in[5];
  const float* attn_b2 = (const float*)d_in[6];
  const float* beta_w  = (const float*)d_in[7];
  const float* beta_b  = (const float*)d_in[8];
  const float* W_ih    = (const float*)d_in[9];
  const float* W_hh    = (const float*)d_in[10];
  const float* b_ih    = (const float*)d_in[11];
  const float* b_hh    = (const float*)d_in[12];
  const float* out_W   = (const float*)d_in[13];
  const float* out_b   = (const float*)d_in[14];
  const float* ih_W1   = (const float*)d_in[15];
  const float* ih_b1   = (const float*)d_in[16];
  const float* ih_W2   = (const float*)d_in[17];
  const float* ih_b2   = (const float*)d_in[18];
  const float* ic_W1   = (const float*)d_in[19];
  const float* ic_b1   = (const float*)d_in[20];
  const float* ic_W2   = (const float*)d_in[21];
  const float* ic_b2   = (const float*)d_in[22];

  float* ws    = (float*)d_ws;
  float* havg  = ws + OFF_HAVG;
  float* tmp   = ws + OFF_TMP;
  float* ht    = ws + OFF_HT;
  float* ct    = ws + OFF_CT;
  float* Hproj = ws + OFF_HPROJ;
  float* Q     = ws + OFF_Q;
  float* u     = ws + OFF_U;
  int*   tok   = (int*)(ws + OFF_TOK);
  ushort* bfb  = (ushort*)(ws + OFF_USH);
  ushort* ht_hi = bfb + U_HT_HI;
  ushort* ht_lo = bfb + U_HT_LO;
  ushort* xc_hi = bfb + U_XC_HI;
  ushort* xc_lo = bfb + U_XC_LO;
  ushort* c2_hi = bfb + U_C2_HI;
  ushort* c2_lo = bfb + U_C2_LO;
  ushort* h_hi  = bfb + U_H_HI;
  ushort* h_lo  = bfb + U_H_LO;
  float* PBUF  = ws + OFF_PBUF;
  float* out   = (float*)d_out;

  // prologue scratch (reuses step-loop ushort areas before their first use)
  ushort* hv_hi = xc_hi;
  ushort* hv_lo = xc_lo;
  ushort* t_hi  = c2_hi;
  ushort* t_lo  = c2_lo;

  auto cdiv = [](int a, int b) { return (a + b - 1) / b; };

  // ws-adaptive split-K (deterministic: ws_size is constant per run)
  const size_t ws_floats = ws_size / 4;
  const size_t pb_cap = (ws_floats > OFF_PBUF) ? (ws_floats - OFF_PBUF) : 0;
  auto clampz = [](size_t v, int lo, int hi) {
    int z = (v > (size_t)hi) ? hi : (int)v;
    return (z < lo) ? lo : z;
  };
  const int zl = clampz(pb_cap / ((size_t)B * V), 1, 20);       // logits
  const int kcl = ((KC + zl - 1) / zl + 7) & ~7;
  const int zg = clampz(pb_cap / ((size_t)B * G4), 1, 16);      // gates
  const int kcg = ((KC + zg - 1) / zg + 7) & ~7;
  const int zq = 25, kcq = 72;                                  // Q: 25*72=1800=K

  // ---- prologue ----
  hmean_kernel<<<cdiv(B * DENC, 256), 256, 0, stream>>>(h, havg);
  split_pad<<<cdiv(B * DENC, 256), 256, 0, stream>>>(havg, DENC, DENC, B, hv_hi, hv_lo);
  // h0: tmp = relu(havg @ ih_W1.T + b1); ht = tmp @ ih_W2.T + b2
  mfma_gemm4<<<dim3(cdiv(DD, 128), 1, 4), 256, 0, stream>>>(
      hv_hi, hv_lo, DENC, ih_W1, DENC, DENC, ih_W1, DENC, PBUF, B, DD, DENC, 128);
  reduce_k<1><<<cdiv(B * DD / 4, 256), 256, 0, stream>>>(
      PBUF, 4, B * DD / 4, (size_t)B * DD, DD, ih_b1, tmp);
  split_pad<<<cdiv(B * DDP, 256), 256, 0, stream>>>(tmp, DD, DDP, B, t_hi, t_lo);
  mfma_gemm4<<<dim3(cdiv(DD, 128), 1, zq), 256, 0, stream>>>(
      t_hi, t_lo, DDP, ih_W2, DD, DD, ih_W2, DD, PBUF, B, DD, DD, kcq);
  reduce_k<0><<<cdiv(B * DD / 4, 256), 256, 0, stream>>>(
      PBUF, zq, B * DD / 4, (size_t)B * DD, DD, ih_b2, ht);
  // c0
  mfma_gemm4<<<dim3(cdiv(DD, 128), 1, 4), 256, 0, stream>>>(
      hv_hi, hv_lo, DENC, ic_W1, DENC, DENC, ic_W1, DENC, PBUF, B, DD, DENC, 128);
  reduce_k<1><<<cdiv(B * DD / 4, 256), 256, 0, stream>>>(
      PBUF, 4, B * DD / 4, (size_t)B * DD, DD, ic_b1, tmp);
  split_pad<<<cdiv(B * DDP, 256), 256, 0, stream>>>(tmp, DD, DDP, B, t_hi, t_lo);
  mfma_gemm4<<<dim3(cdiv(DD, 128), 1, zq), 256, 0, stream>>>(
      t_hi, t_lo, DDP, ic_W2, DD, DD, ic_W2, DD, PBUF, B, DD, DD, kcq);
  reduce_k<0><<<cdiv(B * DD / 4, 256), 256, 0, stream>>>(
      PBUF, zq, B * DD / 4, (size_t)B * DD, DD, ic_b2, ct);
  // splits for step loop
  split_pad<<<cdiv(B * DDP, 256), 256, 0, stream>>>(ht, DD, DDP, B, ht_hi, ht_lo);
  split_pad<<<cdiv(S * B * DENC, 256), 256, 0, stream>>>(h, DENC, DENC, S * B, h_hi, h_lo);
  // Hproj = h @ W1h.T + attn_b1  (z=1, K=512)
  mfma_gemm4<<<dim3(cdiv(DD, 128), S * B / 64, 1), 256, 0, stream>>>(
      h_hi, h_lo, DENC, attn_W1 + DD, DD + DENC, DENC, attn_W1 + DD, DD + DENC,
      Hproj, S * B, DD, DENC, DENC);
  reduce_k<0><<<cdiv(S * B * DD / 4, 256), 256, 0, stream>>>(
      Hproj, 1, S * B * DD / 4, (size_t)S * B * DD, DD, attn_b1, Hproj);
  zero_tok<<<1, 64, 0, stream>>>(tok);

  // ---- decode steps ----
  for (int t = 0; t < T - 1; ++t) {
    // Q = ht @ W1q.T
    mfma_gemm4<<<dim3(cdiv(DD, 128), 1, zq), 256, 0, stream>>>(
        ht_hi, ht_lo, DDP, attn_W1, DD + DENC, DD, attn_W1, DD + DENC,
        PBUF, B, DD, DD, kcq);
    reduce_k<0><<<cdiv(B * DD / 4, 256), 256, 0, stream>>>(
        PBUF, zq, B * DD / 4, (size_t)B * DD, DD, nullptr, Q);
    attn_u_kernel<<<dim3(S, B), 256, 0, stream>>>(Q, Hproj, attn_w2, attn_b2, u);
    softmax_ctx_pack<<<dim3(B, 4), 256, 0, stream>>>(u, h, ht, beta_w, beta_b, emb,
        E + (size_t)t * B, tok, xc_hi, xc_lo, c2_hi, c2_lo);
    // gates = xcat @ [W_ih | W_hh].T
    mfma_gemm4<<<dim3(cdiv(G4, 128), 1, zg), 256, 0, stream>>>(
        xc_hi, xc_lo, KCP, W_ih, DE + DENC, DE + DENC, W_hh, DD,
        PBUF, B, G4, KC, kcg);
    lstm_fused<<<cdiv(B * DD, 256), 256, 0, stream>>>(
        PBUF, zg, b_ih, b_hh, ct, ht, c2_hi, c2_lo, ht_hi, ht_lo);
    // logits = cat2 @ out_W.T -> d_out[t]
    float* logits_t = out + (size_t)t * B * V;
    mfma_gemm4<<<dim3(cdiv(V, 128), 1, zl), 256, 0, stream>>>(
        c2_hi, c2_lo, KCP, out_W, KC, KC, out_W, KC,
        PBUF, B, V, KC, kcl);
    reduce_k<0><<<cdiv(B * V / 4, 256), 256, 0, stream>>>(
        PBUF, zl, B * V / 4, (size_t)B * V, V, out_b, logits_t);
    argmax_kernel<<<B, 256, 0, stream>>>(logits_t, tok);
  }
  (void)in_sizes; (void)n_in; (void)out_size; (void)ws_size;
}

// Round 8
// 3043.546 us; speedup vs baseline: 1.0557x; 1.0557x over previous
//
#include <hip/hip_runtime.h>
#include <hip/hip_bf16.h>
#include <cmath>

// EncoderDecoder: S=49,B=64,DENC=512,DD=1800,DE=512,V=10000,T=20
// Round 8: pre-split ALL weights to bf16 hi/lo planes once per launch
// (ws-gated, ~305 MB; evidence: 441 MB ws poison fill in round-7 profile).
// mfma_gemm5 = pure-bf16 consumer, depth-2 W prefetch, JIT A, no tail.
// Fallback (ws too small) = exact round-6 path via mfma_gemm4.

namespace {

constexpr int S = 49, B = 64, DENC = 512, DD = 1800, DE = 512, V = 10000, T = 20;
constexpr int KC = DD + DE + DENC;   // 2824
constexpr int G4 = 4 * DD;           // 7200
constexpr int KCP = 2848;            // KC padded to %32
constexpr int DDP = 1824;            // DD padded to %32

typedef __attribute__((ext_vector_type(8))) short short8;
typedef __attribute__((ext_vector_type(4))) float f32x4;

__device__ inline float sigf(float x) { return 1.f / (1.f + expf(-x)); }

__device__ inline ushort f2bf_rne(float x) {
  unsigned u = __float_as_uint(x);
  unsigned r = (u + 0x7FFFu + ((u >> 16) & 1u)) >> 16;
  return (ushort)r;
}
__device__ inline void split1(float x, ushort& h, ushort& l) {
  h = f2bf_rne(x);
  float hf = __uint_as_float(((unsigned)h) << 16);
  l = f2bf_rne(x - hf);
}
__device__ inline void split8(float4 a, float4 b, short8& hi, short8& lo) {
  float v[8] = {a.x, a.y, a.z, a.w, b.x, b.y, b.z, b.w};
#pragma unroll
  for (int i = 0; i < 8; ++i) {
    ushort h, l; split1(v[i], h, l);
    hi[i] = (short)h; lo[i] = (short)l;
  }
}

// ---------------- h_avg = mean_s h[s,b,:] ----------------
__global__ __launch_bounds__(256) void hmean_kernel(const float* __restrict__ h,
                                                    float* __restrict__ h_avg) {
  int idx = blockIdx.x * 256 + threadIdx.x;
  if (idx >= B * DENC) return;
  float s = 0.f;
  for (int si = 0; si < S; ++si) s += h[(size_t)si * B * DENC + idx];
  h_avg[idx] = s * (1.0f / (float)S);
}

// ---------------- MFMA bf16x3 GEMM v5: pre-split W planes ----------------
// C[m,n] = sum_k A[m,k]*W[n,k]. A and W both pre-split bf16 hi/lo planes,
// zero-padded to KP (%32, same stride for A and W). Depth-2 W prefetch,
// JIT A loads. kchunk%32==0. All-z-busy required (z*kchunk layout covers KP,
// (z-1)*kchunk < KP). A zero-pad means padding k contributes 0. M%64==0.
__global__ __launch_bounds__(256) void mfma_gemm5(
    const ushort* __restrict__ Ahi, const ushort* __restrict__ Alo,
    const ushort* __restrict__ Whi, const ushort* __restrict__ Wlo,
    int KP, float* __restrict__ P, int M, int N, int kchunk) {
  const int lane = threadIdx.x & 63;
  const int wv = threadIdx.x >> 6;
  const int nbase = blockIdx.x * 128 + wv * 32;
  const int bm = blockIdx.y * 64;
  const int z = blockIdx.z;
  const int row = lane & 15;
  const int kg = (lane >> 4) * 8;
  const int k_begin = z * kchunk;
  const int k_end = min(KP, k_begin + kchunk);

  const int n0 = nbase + row, n1 = n0 + 16;
  const int nc0 = (n0 < N) ? n0 : (N - 1);
  const int nc1 = (n1 < N) ? n1 : (N - 1);

  const ushort* pa_hi = Ahi + (size_t)(bm + row) * KP + kg;
  const ushort* pa_lo = Alo + (size_t)(bm + row) * KP + kg;
  const ushort* pw0h = Whi + (size_t)nc0 * KP + kg;
  const ushort* pw0l = Wlo + (size_t)nc0 * KP + kg;
  const ushort* pw1h = Whi + (size_t)nc1 * KP + kg;
  const ushort* pw1l = Wlo + (size_t)nc1 * KP + kg;

  f32x4 acc[2][4] = {};

  auto loadW = [&](int kk, short8* s) {
    s[0] = *(const short8*)(pw0h + kk);
    s[1] = *(const short8*)(pw0l + kk);
    s[2] = *(const short8*)(pw1h + kk);
    s[3] = *(const short8*)(pw1l + kk);
  };
  auto loadA = [&](int kk, short8* ah, short8* al) {
#pragma unroll
    for (int ms = 0; ms < 4; ++ms) {
      ah[ms] = *(const short8*)(pa_hi + (size_t)(ms * 16) * KP + kk);
      al[ms] = *(const short8*)(pa_lo + (size_t)(ms * 16) * KP + kk);
    }
  };
  auto block = [&](const short8* ah, const short8* al, const short8* w) {
#pragma unroll
    for (int ms = 0; ms < 4; ++ms) {
      acc[0][ms] = __builtin_amdgcn_mfma_f32_16x16x32_bf16(ah[ms], w[0], acc[0][ms], 0, 0, 0);
      acc[0][ms] = __builtin_amdgcn_mfma_f32_16x16x32_bf16(al[ms], w[0], acc[0][ms], 0, 0, 0);
      acc[0][ms] = __builtin_amdgcn_mfma_f32_16x16x32_bf16(ah[ms], w[1], acc[0][ms], 0, 0, 0);
      acc[1][ms] = __builtin_amdgcn_mfma_f32_16x16x32_bf16(ah[ms], w[2], acc[1][ms], 0, 0, 0);
      acc[1][ms] = __builtin_amdgcn_mfma_f32_16x16x32_bf16(al[ms], w[2], acc[1][ms], 0, 0, 0);
      acc[1][ms] = __builtin_amdgcn_mfma_f32_16x16x32_bf16(ah[ms], w[3], acc[1][ms], 0, 0, 0);
    }
  };

  const int nf = (k_end > k_begin) ? ((k_end - k_begin) >> 5) : 0;
  short8 s0[4], s1[4];
  if (nf > 0) loadW(k_begin, s0);
  if (nf > 1) loadW(k_begin + 32, s1);
  int it = 0;
  for (; it + 1 < nf; it += 2) {
    short8 ah[4], al[4], c[4];
    loadA(k_begin + it * 32, ah, al);
    c[0] = s0[0]; c[1] = s0[1]; c[2] = s0[2]; c[3] = s0[3];
    if (it + 2 < nf) loadW(k_begin + (it + 2) * 32, s0);
    block(ah, al, c);
    loadA(k_begin + (it + 1) * 32, ah, al);
    c[0] = s1[0]; c[1] = s1[1]; c[2] = s1[2]; c[3] = s1[3];
    if (it + 3 < nf) loadW(k_begin + (it + 3) * 32, s1);
    block(ah, al, c);
  }
  if (it < nf) {  // odd remainder: always slot s0 (loaded at it or refreshed)
    short8 ah[4], al[4];
    loadA(k_begin + it * 32, ah, al);
    block(ah, al, s0);
  }

  float* Pz = P + (size_t)z * ((size_t)M * N);
#pragma unroll
  for (int j = 0; j < 2; ++j) {
    int n = nbase + j * 16 + row;
    if (n >= N) continue;
#pragma unroll
    for (int ms = 0; ms < 4; ++ms) {
      int r0 = bm + ms * 16 + (lane >> 4) * 4;
#pragma unroll
      for (int r = 0; r < 4; ++r) {
        Pz[(size_t)(r0 + r) * N + n] = acc[j][ms][r];
      }
    }
  }
}

// ---------------- MFMA bf16x3 GEMM v4 (fallback): in-register W split ----
__global__ __launch_bounds__(256) void mfma_gemm4(
    const ushort* __restrict__ Ahi, const ushort* __restrict__ Alo, int ldap,
    const float* __restrict__ Wa, int ldwa, int Ka,
    const float* __restrict__ Wb, int ldwb,
    float* __restrict__ P, int M, int N, int K, int kchunk) {
  const int lane = threadIdx.x & 63;
  const int wv = threadIdx.x >> 6;
  const int nbase = blockIdx.x * 128 + wv * 32;
  const int bm = blockIdx.y * 64;
  const int z = blockIdx.z;
  const int row = lane & 15;
  const int kg = (lane >> 4) * 8;
  const int k_begin = z * kchunk;
  const int k_end = min(K, k_begin + kchunk);

  const int n0 = nbase + row, n1 = n0 + 16;
  const int nc0 = (n0 < N) ? n0 : (N - 1);
  const int nc1 = (n1 < N) ? n1 : (N - 1);

  const ushort* pa_hi = Ahi + (size_t)(bm + row) * ldap + kg;
  const ushort* pa_lo = Alo + (size_t)(bm + row) * ldap + kg;

  f32x4 acc[2][4] = {};

  auto wptr = [&](int nc, int k) -> const float* {
    return (k < Ka) ? (Wa + (size_t)nc * ldwa + k)
                    : (Wb + (size_t)nc * ldwb + (k - Ka));
  };
  auto loadW2 = [&](int kk, float4* w) {
    const float* p0 = wptr(nc0, kk + kg);
    const float* p1 = wptr(nc1, kk + kg);
    w[0] = *(const float4*)p0; w[1] = *(const float4*)(p0 + 4);
    w[2] = *(const float4*)p1; w[3] = *(const float4*)(p1 + 4);
  };
  auto loadA = [&](int kk, short8* ah, short8* al) {
#pragma unroll
    for (int ms = 0; ms < 4; ++ms) {
      ah[ms] = *(const short8*)(pa_hi + (size_t)(ms * 16) * ldap + kk);
      al[ms] = *(const short8*)(pa_lo + (size_t)(ms * 16) * ldap + kk);
    }
  };

  const int nfull = (k_end > k_begin) ? ((k_end - k_begin) >> 5) : 0;
  float4 cw[4];
  if (nfull) loadW2(k_begin, cw);
  for (int it = 0; it < nfull; ++it) {
    const int kk = k_begin + it * 32;
    short8 ah[4], al[4];
    loadA(kk, ah, al);
    const bool more = (it + 1 < nfull);
    float4 nw[4];
    if (more) loadW2(kk + 32, nw);
    short8 wh0, wl0, wh1, wl1;
    split8(cw[0], cw[1], wh0, wl0);
    split8(cw[2], cw[3], wh1, wl1);
#pragma unroll
    for (int ms = 0; ms < 4; ++ms) {
      acc[0][ms] = __builtin_amdgcn_mfma_f32_16x16x32_bf16(ah[ms], wh0, acc[0][ms], 0, 0, 0);
      acc[0][ms] = __builtin_amdgcn_mfma_f32_16x16x32_bf16(al[ms], wh0, acc[0][ms], 0, 0, 0);
      acc[0][ms] = __builtin_amdgcn_mfma_f32_16x16x32_bf16(ah[ms], wl0, acc[0][ms], 0, 0, 0);
      acc[1][ms] = __builtin_amdgcn_mfma_f32_16x16x32_bf16(ah[ms], wh1, acc[1][ms], 0, 0, 0);
      acc[1][ms] = __builtin_amdgcn_mfma_f32_16x16x32_bf16(al[ms], wh1, acc[1][ms], 0, 0, 0);
      acc[1][ms] = __builtin_amdgcn_mfma_f32_16x16x32_bf16(ah[ms], wl1, acc[1][ms], 0, 0, 0);
    }
    if (more) {
#pragma unroll
      for (int q = 0; q < 4; ++q) cw[q] = nw[q];
    }
  }
  const int ktail = k_begin + nfull * 32;
  if (ktail < k_end) {
    int rem = k_end - ktail;
    short8 wh0 = {}, wl0 = {}, wh1 = {}, wl1 = {};
    if (kg < rem) {
      float4 w[4];
      loadW2(ktail, w);
      split8(w[0], w[1], wh0, wl0);
      split8(w[2], w[3], wh1, wl1);
    }
    short8 tah[4], tal[4];
    loadA(ktail, tah, tal);
#pragma unroll
    for (int ms = 0; ms < 4; ++ms) {
      acc[0][ms] = __builtin_amdgcn_mfma_f32_16x16x32_bf16(tah[ms], wh0, acc[0][ms], 0, 0, 0);
      acc[0][ms] = __builtin_amdgcn_mfma_f32_16x16x32_bf16(tal[ms], wh0, acc[0][ms], 0, 0, 0);
      acc[0][ms] = __builtin_amdgcn_mfma_f32_16x16x32_bf16(tah[ms], wl0, acc[0][ms], 0, 0, 0);
      acc[1][ms] = __builtin_amdgcn_mfma_f32_16x16x32_bf16(tah[ms], wh1, acc[1][ms], 0, 0, 0);
      acc[1][ms] = __builtin_amdgcn_mfma_f32_16x16x32_bf16(tal[ms], wh1, acc[1][ms], 0, 0, 0);
      acc[1][ms] = __builtin_amdgcn_mfma_f32_16x16x32_bf16(tah[ms], wl1, acc[1][ms], 0, 0, 0);
    }
  }

  float* Pz = P + (size_t)z * ((size_t)M * N);
#pragma unroll
  for (int j = 0; j < 2; ++j) {
    int n = nbase + j * 16 + row;
    if (n >= N) continue;
#pragma unroll
    for (int ms = 0; ms < 4; ++ms) {
      int r0 = bm + ms * 16 + (lane >> 4) * 4;
#pragma unroll
      for (int r = 0; r < 4; ++r) {
        Pz[(size_t)(r0 + r) * N + n] = acc[j][ms][r];
      }
    }
  }
}

// ---------------- reduce over split-K partials (+bias, +relu) ----------------
template <int ACT>
__global__ __launch_bounds__(256) void reduce_k(const float* __restrict__ P, int nz,
                                                int total4, size_t MN, int N,
                                                const float* __restrict__ bias,
                                                float* __restrict__ C) {
  int i4 = blockIdx.x * 256 + threadIdx.x;
  if (i4 >= total4) return;
  size_t idx = (size_t)i4 * 4;
  float4 s = *(const float4*)(P + idx);
  for (int zz = 1; zz < nz; ++zz) {
    float4 t = *(const float4*)(P + (size_t)zz * MN + idx);
    s.x += t.x; s.y += t.y; s.z += t.z; s.w += t.w;
  }
  if (bias) {
    int nn = (int)(idx % (size_t)N);
    s.x += bias[nn]; s.y += bias[nn + 1]; s.z += bias[nn + 2]; s.w += bias[nn + 3];
  }
  if (ACT == 1) {
    s.x = fmaxf(s.x, 0.f); s.y = fmaxf(s.y, 0.f);
    s.z = fmaxf(s.z, 0.f); s.w = fmaxf(s.w, 0.f);
  }
  *(float4*)(C + idx) = s;
}

// ---------------- split fp32 rows -> bf16 hi/lo with zero pad ----------------
__global__ __launch_bounds__(256) void split_pad(const float* __restrict__ src, int K,
                                                 int KP, int rows,
                                                 ushort* __restrict__ hi,
                                                 ushort* __restrict__ lo) {
  int idx = blockIdx.x * 256 + threadIdx.x;
  if (idx >= rows * KP) return;
  int r = idx / KP, k = idx % KP;
  ushort h = 0, l = 0;
  if (k < K) split1(src[(size_t)r * K + k], h, l);
  hi[idx] = h; lo[idx] = l;
}

// ---------------- split two-segment weight rows -> padded bf16 hi/lo ----------
__global__ __launch_bounds__(256) void split_wseg(
    const float* __restrict__ Wa, int ldwa, int Ka,
    const float* __restrict__ Wb, int ldwb, int Kb,
    int rows, int KP, ushort* __restrict__ hi, ushort* __restrict__ lo) {
  int idx = blockIdx.x * 256 + threadIdx.x;
  if (idx >= rows * KP) return;
  int r = idx / KP, k = idx - r * KP;
  float v = 0.f;
  if (k < Ka) v = Wa[(size_t)r * ldwa + k];
  else if (k < Ka + Kb) v = Wb[(size_t)r * ldwb + (k - Ka)];
  ushort h, l; split1(v, h, l);
  hi[idx] = h; lo[idx] = l;
}

// ---------------- u[s,b] = relu(Q[b,:] + Hproj[s,b,:]) . w2 + b2 ----------------
__global__ __launch_bounds__(256) void attn_u_kernel(const float* __restrict__ Q,
                                                     const float* __restrict__ Hproj,
                                                     const float* __restrict__ w2,
                                                     const float* __restrict__ b2,
                                                     float* __restrict__ u) {
  int s = blockIdx.x, b = blockIdx.y;
  const float4* q4 = (const float4*)(Q + (size_t)b * DD);
  const float4* h4 = (const float4*)(Hproj + ((size_t)s * B + b) * DD);
  const float4* w4 = (const float4*)w2;
  float acc = 0.f;
  for (int i = threadIdx.x; i < DD / 4; i += 256) {
    float4 q = q4[i], hh = h4[i], w = w4[i];
    acc += fmaxf(q.x + hh.x, 0.f) * w.x + fmaxf(q.y + hh.y, 0.f) * w.y +
           fmaxf(q.z + hh.z, 0.f) * w.z + fmaxf(q.w + hh.w, 0.f) * w.w;
  }
  for (int off = 32; off; off >>= 1) acc += __shfl_xor(acc, off);
  __shared__ float red[4];
  if ((threadIdx.x & 63) == 0) red[threadIdx.x >> 6] = acc;
  __syncthreads();
  if (threadIdx.x == 0) u[s * B + b] = red[0] + red[1] + red[2] + red[3] + b2[0];
}

// ---------------- per-(b,slice): softmax, beta; slice of ctx + packing ----------------
__global__ __launch_bounds__(256) void softmax_ctx_pack(
    const float* __restrict__ u, const float* __restrict__ h,
    const float* __restrict__ ht, const float* __restrict__ beta_w,
    const float* __restrict__ beta_b, const float* __restrict__ emb,
    const int* __restrict__ Et, const int* __restrict__ prev_tok,
    ushort* __restrict__ xcat_hi, ushort* __restrict__ xcat_lo,
    ushort* __restrict__ cat2_hi, ushort* __restrict__ cat2_lo) {
  int b = blockIdx.x, slice = blockIdx.y, tid = threadIdx.x;
  __shared__ float a_sh[S];
  __shared__ float red[4];
  float uv = (tid < S) ? u[tid * B + b] : -INFINITY;
  float m = uv;
  for (int off = 32; off; off >>= 1) m = fmaxf(m, __shfl_xor(m, off));
  if ((tid & 63) == 0) red[tid >> 6] = m;
  __syncthreads();
  m = fmaxf(fmaxf(red[0], red[1]), fmaxf(red[2], red[3]));
  float e = (tid < S) ? expf(uv - m) : 0.f;
  float ssum = e;
  for (int off = 32; off; off >>= 1) ssum += __shfl_xor(ssum, off);
  __syncthreads();
  if ((tid & 63) == 0) red[tid >> 6] = ssum;
  __syncthreads();
  ssum = red[0] + red[1] + red[2] + red[3];
  if (tid < S) a_sh[tid] = e / ssum;
  float acc = 0.f;
  {
    const float4* h4 = (const float4*)(ht + (size_t)b * DD);
    const float4* w4 = (const float4*)beta_w;
    for (int i = tid; i < DD / 4; i += 256) {
      float4 x = h4[i], w = w4[i];
      acc += x.x * w.x + x.y * w.y + x.z * w.z + x.w * w.w;
    }
  }
  for (int off = 32; off; off >>= 1) acc += __shfl_xor(acc, off);
  __syncthreads();
  if ((tid & 63) == 0) red[tid >> 6] = acc;
  __syncthreads();
  float beta = sigf(red[0] + red[1] + red[2] + red[3] + beta_b[0]);

  const size_t xb = (size_t)b * KCP;
  for (int e0 = slice * 128 + tid; e0 < slice * 128 + 128; e0 += 256) {
    float c = 0.f;
    for (int si = 0; si < S; ++si) c += a_sh[si] * h[((size_t)si * B + b) * DENC + e0];
    c *= beta;
    ushort hh, ll; split1(c, hh, ll);
    xcat_hi[xb + DE + e0] = hh;      xcat_lo[xb + DE + e0] = ll;
    cat2_hi[xb + DD + DE + e0] = hh; cat2_lo[xb + DD + DE + e0] = ll;
  }
  int et = Et[b];
  int pt = prev_tok[b];
  for (int e0 = slice * 128 + tid; e0 < slice * 128 + 128; e0 += 256) {
    ushort hh, ll;
    split1(emb[(size_t)et * DE + e0], hh, ll);
    xcat_hi[xb + e0] = hh; xcat_lo[xb + e0] = ll;
    split1(emb[(size_t)pt * DE + e0], hh, ll);
    cat2_hi[xb + DD + e0] = hh; cat2_lo[xb + DD + e0] = ll;
  }
  for (int j = slice * 450 + tid; j < slice * 450 + 450; j += 256) {
    ushort hh, ll; split1(ht[(size_t)b * DD + j], hh, ll);
    xcat_hi[xb + DE + DENC + j] = hh; xcat_lo[xb + DE + DENC + j] = ll;
  }
  if (slice == 3 && tid < KCP - KC) {
    xcat_hi[xb + KC + tid] = 0; xcat_lo[xb + KC + tid] = 0;
    cat2_hi[xb + KC + tid] = 0; cat2_lo[xb + KC + tid] = 0;
  }
}

// ---------------- LSTM: reduce gates partials + update + bf16 splits ----------------
__global__ __launch_bounds__(256) void lstm_fused(
    const float* __restrict__ P, int nz, const float* __restrict__ b_ih,
    const float* __restrict__ b_hh, float* __restrict__ ct, float* __restrict__ ht,
    ushort* __restrict__ cat2_hi, ushort* __restrict__ cat2_lo,
    ushort* __restrict__ ht_hi, ushort* __restrict__ ht_lo) {
  int idx = blockIdx.x * 256 + threadIdx.x;
  if (idx >= B * DD) return;
  int b = idx / DD, d = idx % DD;
  const size_t MN = (size_t)B * G4;
  float g0 = 0.f, g1 = 0.f, g2 = 0.f, g3 = 0.f;
  for (int zz = 0; zz < nz; ++zz) {
    const float* g = P + (size_t)zz * MN + (size_t)b * G4;
    g0 += g[d]; g1 += g[DD + d]; g2 += g[2 * DD + d]; g3 += g[3 * DD + d];
  }
  g0 += b_ih[d] + b_hh[d];
  g1 += b_ih[DD + d] + b_hh[DD + d];
  g2 += b_ih[2 * DD + d] + b_hh[2 * DD + d];
  g3 += b_ih[3 * DD + d] + b_hh[3 * DD + d];
  float c = sigf(g1) * ct[idx] + sigf(g0) * tanhf(g2);
  float hn = sigf(g3) * tanhf(c);
  ct[idx] = c;
  ht[idx] = hn;
  ushort hh, ll; split1(hn, hh, ll);
  cat2_hi[(size_t)b * KCP + d] = hh; cat2_lo[(size_t)b * KCP + d] = ll;
  ht_hi[(size_t)b * DDP + d] = hh;   ht_lo[(size_t)b * DDP + d] = ll;
  if (d < DDP - DD) {
    ht_hi[(size_t)b * DDP + DD + d] = 0; ht_lo[(size_t)b * DDP + DD + d] = 0;
  }
}

// ---------------- per-b argmax over V ----------------
__global__ __launch_bounds__(256) void argmax_kernel(const float* __restrict__ logits,
                                                     int* __restrict__ tok) {
  int b = blockIdx.x;
  const float* row = logits + (size_t)b * V;
  float best = -INFINITY;
  int bi = 0x7fffffff;
  for (int v = threadIdx.x; v < V; v += 256) {
    float x = row[v];
    if (x > best) { best = x; bi = v; }
  }
  for (int off = 32; off; off >>= 1) {
    float ov = __shfl_xor(best, off);
    int oi = __shfl_xor(bi, off);
    if (ov > best || (ov == best && oi < bi)) { best = ov; bi = oi; }
  }
  __shared__ float bv[4];
  __shared__ int bix[4];
  if ((threadIdx.x & 63) == 0) { bv[threadIdx.x >> 6] = best; bix[threadIdx.x >> 6] = bi; }
  __syncthreads();
  if (threadIdx.x == 0) {
    for (int w = 1; w < 4; ++w)
      if (bv[w] > best || (bv[w] == best && bix[w] < bi)) { best = bv[w]; bi = bix[w]; }
    tok[b] = bi;
  }
}

__global__ void zero_tok(int* tok) { if (threadIdx.x < B) tok[threadIdx.x] = 0; }

// ---- ws layout (float offsets): fp32 region | PBUF | ushort area ----
constexpr size_t OFF_HAVG  = 0;
constexpr size_t OFF_TMP   = OFF_HAVG + 32768;
constexpr size_t OFF_HT    = OFF_TMP + 115200;
constexpr size_t OFF_CT    = OFF_HT + 115200;
constexpr size_t OFF_HPROJ = OFF_CT + 115200;         // 3136*1800
constexpr size_t OFF_Q     = OFF_HPROJ + 5644800;
constexpr size_t OFF_U     = OFF_Q + 115200;
constexpr size_t OFF_TOK   = OFF_U + 3200;
constexpr size_t OFF_PBUF  = OFF_TOK + 128;           // 6,141,696
constexpr size_t PBUF_F    = 6400000;                 // max z=10 * B*V
constexpr size_t OFF_USH   = OFF_PBUF + PBUF_F;       // 12,541,696 (floats)

// ushort offsets within ushort area
constexpr size_t U_HT_HI  = 0;
constexpr size_t U_HT_LO  = U_HT_HI + (size_t)B * DDP;        // +116,736
constexpr size_t U_XC_HI  = U_HT_LO + (size_t)B * DDP;
constexpr size_t U_XC_LO  = U_XC_HI + (size_t)B * KCP;        // +182,272
constexpr size_t U_C2_HI  = U_XC_LO + (size_t)B * KCP;
constexpr size_t U_C2_LO  = U_C2_HI + (size_t)B * KCP;
constexpr size_t U_H_HI   = U_C2_LO + (size_t)B * KCP;
constexpr size_t U_H_LO   = U_H_HI + (size_t)(S * B) * DENC;  // +1,605,632
constexpr size_t U_ACTEND = U_H_LO + (size_t)(S * B) * DENC;  // 4,173,824
// weight planes (pre path only)
constexpr size_t U_OW_HI  = U_ACTEND;
constexpr size_t U_OW_LO  = U_OW_HI + (size_t)V * KCP;        // +28,480,000
constexpr size_t U_WG_HI  = U_OW_LO + (size_t)V * KCP;
constexpr size_t U_WG_LO  = U_WG_HI + (size_t)G4 * KCP;       // +20,505,600
constexpr size_t U_WQ_HI  = U_WG_LO + (size_t)G4 * KCP;
constexpr size_t U_WQ_LO  = U_WQ_HI + (size_t)DD * DDP;       // +3,283,200
constexpr size_t U_WH_HI  = U_WQ_LO + (size_t)DD * DDP;
constexpr size_t U_WH_LO  = U_WH_HI + (size_t)DD * DENC;      // +921,600
constexpr size_t U_I1H    = U_WH_LO + (size_t)DD * DENC;      // ih_W1 hi
constexpr size_t U_I1L    = U_I1H + (size_t)DD * DENC;
constexpr size_t U_I2H    = U_I1L + (size_t)DD * DENC;        // ih_W2 hi
constexpr size_t U_I2L    = U_I2H + (size_t)DD * DDP;
constexpr size_t U_C1H    = U_I2L + (size_t)DD * DDP;         // ic_W1 hi
constexpr size_t U_C1L    = U_C1H + (size_t)DD * DENC;
constexpr size_t U_C2H    = U_C1L + (size_t)DD * DENC;        // ic_W2 hi
constexpr size_t U_C2L    = U_C2H + (size_t)DD * DDP;
constexpr size_t U_END    = U_C2L + (size_t)DD * DDP;         // 127,373,824

constexpr size_t NEED_FB  = OFF_USH * 4 + U_ACTEND * 2;       // 58,514,432 (proven fits)
constexpr size_t NEED_PRE = OFF_USH * 4 + U_END * 2;          // 304,914,432

}  // namespace

extern "C" void kernel_launch(void* const* d_in, const int* in_sizes, int n_in,
                              void* d_out, int out_size, void* d_ws, size_t ws_size,
                              hipStream_t stream) {
  const float* h       = (const float*)d_in[0];
  const int*   E       = (const int*)d_in[1];
  const float* emb     = (const float*)d_in[2];
  const float* attn_W1 = (const float*)d_in[3];
  const float* attn_b1 = (const float*)d_in[4];
  const float* attn_w2 = (const float*)d_in[5];
  const float* attn_b2 = (const float*)d_in[6];
  const float* beta_w  = (const float*)d_in[7];
  const float* beta_b  = (const float*)d_in[8];
  const float* W_ih    = (const float*)d_in[9];
  const float* W_hh    = (const float*)d_in[10];
  const float* b_ih    = (const float*)d_in[11];
  const float* b_hh    = (const float*)d_in[12];
  const float* out_W   = (const float*)d_in[13];
  const float* out_b   = (const float*)d_in[14];
  const float* ih_W1   = (const float*)d_in[15];
  const float* ih_b1   = (const float*)d_in[16];
  const float* ih_W2   = (const float*)d_in[17];
  const float* ih_b2   = (const float*)d_in[18];
  const float* ic_W1   = (const float*)d_in[19];
  const float* ic_b1   = (const float*)d_in[20];
  const float* ic_W2   = (const float*)d_in[21];
  const float* ic_b2   = (const float*)d_in[22];

  float* ws    = (float*)d_ws;
  float* havg  = ws + OFF_HAVG;
  float* tmp   = ws + OFF_TMP;
  float* ht    = ws + OFF_HT;
  float* ct    = ws + OFF_CT;
  float* Hproj = ws + OFF_HPROJ;
  float* Q     = ws + OFF_Q;
  float* u     = ws + OFF_U;
  int*   tok   = (int*)(ws + OFF_TOK);
  float* PBUF  = ws + OFF_PBUF;
  ushort* bfb  = (ushort*)(ws + OFF_USH);
  ushort* ht_hi = bfb + U_HT_HI;
  ushort* ht_lo = bfb + U_HT_LO;
  ushort* xc_hi = bfb + U_XC_HI;
  ushort* xc_lo = bfb + U_XC_LO;
  ushort* c2_hi = bfb + U_C2_HI;
  ushort* c2_lo = bfb + U_C2_LO;
  ushort* h_hi  = bfb + U_H_HI;
  ushort* h_lo  = bfb + U_H_LO;
  ushort* ow_h  = bfb + U_OW_HI;
  ushort* ow_l  = bfb + U_OW_LO;
  ushort* wg_h  = bfb + U_WG_HI;
  ushort* wg_l  = bfb + U_WG_LO;
  ushort* wq_h  = bfb + U_WQ_HI;
  ushort* wq_l  = bfb + U_WQ_LO;
  ushort* whp_h = bfb + U_WH_HI;
  ushort* whp_l = bfb + U_WH_LO;
  ushort* i1h   = bfb + U_I1H;
  ushort* i1l   = bfb + U_I1L;
  ushort* i2h   = bfb + U_I2H;
  ushort* i2l   = bfb + U_I2L;
  ushort* c1h   = bfb + U_C1H;
  ushort* c1l   = bfb + U_C1L;
  ushort* c2h_w = bfb + U_C2H;
  ushort* c2l_w = bfb + U_C2L;
  float* out   = (float*)d_out;

  // prologue scratch (reuses step-loop activation areas before first step)
  ushort* hv_hi = xc_hi;   // havg planes, KP=512 (fits 64*2848)
  ushort* hv_lo = xc_lo;
  ushort* t_hi  = c2_hi;   // tmp planes, KP=1824
  ushort* t_lo  = c2_lo;

  auto cdiv = [](int a, int b) { return (a + b - 1) / b; };
  const bool pre = (ws_size >= NEED_PRE);

  // ---- prologue ----
  hmean_kernel<<<cdiv(B * DENC, 256), 256, 0, stream>>>(h, havg);
  split_pad<<<cdiv(B * DENC, 256), 256, 0, stream>>>(havg, DENC, DENC, B, hv_hi, hv_lo);

  if (pre) {
    // one-time-per-launch weight plane splits
    split_wseg<<<cdiv(V * KCP, 256), 256, 0, stream>>>(
        out_W, KC, KC, nullptr, 0, 0, V, KCP, ow_h, ow_l);
    split_wseg<<<cdiv(G4 * KCP, 256), 256, 0, stream>>>(
        W_ih, DE + DENC, DE + DENC, W_hh, DD, DD, G4, KCP, wg_h, wg_l);
    split_wseg<<<cdiv(DD * DDP, 256), 256, 0, stream>>>(
        attn_W1, DD + DENC, DD, nullptr, 0, 0, DD, DDP, wq_h, wq_l);
    split_wseg<<<cdiv(DD * DENC, 256), 256, 0, stream>>>(
        attn_W1 + DD, DD + DENC, DENC, nullptr, 0, 0, DD, DENC, whp_h, whp_l);
    split_wseg<<<cdiv(DD * DENC, 256), 256, 0, stream>>>(
        ih_W1, DENC, DENC, nullptr, 0, 0, DD, DENC, i1h, i1l);
    split_wseg<<<cdiv(DD * DDP, 256), 256, 0, stream>>>(
        ih_W2, DD, DD, nullptr, 0, 0, DD, DDP, i2h, i2l);
    split_wseg<<<cdiv(DD * DENC, 256), 256, 0, stream>>>(
        ic_W1, DENC, DENC, nullptr, 0, 0, DD, DENC, c1h, c1l);
    split_wseg<<<cdiv(DD * DDP, 256), 256, 0, stream>>>(
        ic_W2, DD, DD, nullptr, 0, 0, DD, DDP, c2h_w, c2l_w);
  }

  // h0/c0
  if (pre) {
    mfma_gemm5<<<dim3(cdiv(DD, 128), 1, 4), 256, 0, stream>>>(
        hv_hi, hv_lo, i1h, i1l, DENC, PBUF, B, DD, 128);
    reduce_k<1><<<cdiv(B * DD / 4, 256), 256, 0, stream>>>(
        PBUF, 4, B * DD / 4, (size_t)B * DD, DD, ih_b1, tmp);
    split_pad<<<cdiv(B * DDP, 256), 256, 0, stream>>>(tmp, DD, DDP, B, t_hi, t_lo);
    mfma_gemm5<<<dim3(cdiv(DD, 128), 1, 19), 256, 0, stream>>>(
        t_hi, t_lo, i2h, i2l, DDP, PBUF, B, DD, 96);
    reduce_k<0><<<cdiv(B * DD / 4, 256), 256, 0, stream>>>(
        PBUF, 19, B * DD / 4, (size_t)B * DD, DD, ih_b2, ht);
    mfma_gemm5<<<dim3(cdiv(DD, 128), 1, 4), 256, 0, stream>>>(
        hv_hi, hv_lo, c1h, c1l, DENC, PBUF, B, DD, 128);
    reduce_k<1><<<cdiv(B * DD / 4, 256), 256, 0, stream>>>(
        PBUF, 4, B * DD / 4, (size_t)B * DD, DD, ic_b1, tmp);
    split_pad<<<cdiv(B * DDP, 256), 256, 0, stream>>>(tmp, DD, DDP, B, t_hi, t_lo);
    mfma_gemm5<<<dim3(cdiv(DD, 128), 1, 19), 256, 0, stream>>>(
        t_hi, t_lo, c2h_w, c2l_w, DDP, PBUF, B, DD, 96);
    reduce_k<0><<<cdiv(B * DD / 4, 256), 256, 0, stream>>>(
        PBUF, 19, B * DD / 4, (size_t)B * DD, DD, ic_b2, ct);
  } else {
    mfma_gemm4<<<dim3(cdiv(DD, 128), 1, 4), 256, 0, stream>>>(
        hv_hi, hv_lo, DENC, ih_W1, DENC, DENC, ih_W1, DENC, PBUF, B, DD, DENC, 128);
    reduce_k<1><<<cdiv(B * DD / 4, 256), 256, 0, stream>>>(
        PBUF, 4, B * DD / 4, (size_t)B * DD, DD, ih_b1, tmp);
    split_pad<<<cdiv(B * DDP, 256), 256, 0, stream>>>(tmp, DD, DDP, B, t_hi, t_lo);
    mfma_gemm4<<<dim3(cdiv(DD, 128), 1, 15), 256, 0, stream>>>(
        t_hi, t_lo, DDP, ih_W2, DD, DD, ih_W2, DD, PBUF, B, DD, DD, 120);
    reduce_k<0><<<cdiv(B * DD / 4, 256), 256, 0, stream>>>(
        PBUF, 15, B * DD / 4, (size_t)B * DD, DD, ih_b2, ht);
    mfma_gemm4<<<dim3(cdiv(DD, 128), 1, 4), 256, 0, stream>>>(
        hv_hi, hv_lo, DENC, ic_W1, DENC, DENC, ic_W1, DENC, PBUF, B, DD, DENC, 128);
    reduce_k<1><<<cdiv(B * DD / 4, 256), 256, 0, stream>>>(
        PBUF, 4, B * DD / 4, (size_t)B * DD, DD, ic_b1, tmp);
    split_pad<<<cdiv(B * DDP, 256), 256, 0, stream>>>(tmp, DD, DDP, B, t_hi, t_lo);
    mfma_gemm4<<<dim3(cdiv(DD, 128), 1, 15), 256, 0, stream>>>(
        t_hi, t_lo, DDP, ic_W2, DD, DD, ic_W2, DD, PBUF, B, DD, DD, 120);
    reduce_k<0><<<cdiv(B * DD / 4, 256), 256, 0, stream>>>(
        PBUF, 15, B * DD / 4, (size_t)B * DD, DD, ic_b2, ct);
  }

  split_pad<<<cdiv(B * DDP, 256), 256, 0, stream>>>(ht, DD, DDP, B, ht_hi, ht_lo);
  split_pad<<<cdiv(S * B * DENC, 256), 256, 0, stream>>>(h, DENC, DENC, S * B, h_hi, h_lo);
  // Hproj = h @ W1h.T + attn_b1
  if (pre) {
    mfma_gemm5<<<dim3(cdiv(DD, 128), S * B / 64, 1), 256, 0, stream>>>(
        h_hi, h_lo, whp_h, whp_l, DENC, Hproj, S * B, DD, DENC);
  } else {
    mfma_gemm4<<<dim3(cdiv(DD, 128), S * B / 64, 1), 256, 0, stream>>>(
        h_hi, h_lo, DENC, attn_W1 + DD, DD + DENC, DENC, attn_W1 + DD, DD + DENC,
        Hproj, S * B, DD, DENC, DENC);
  }
  reduce_k<0><<<cdiv(S * B * DD / 4, 256), 256, 0, stream>>>(
      Hproj, 1, S * B * DD / 4, (size_t)S * B * DD, DD, attn_b1, Hproj);
  zero_tok<<<1, 64, 0, stream>>>(tok);

  const int zq = pre ? 19 : 15;
  // ---- decode steps ----
  for (int t = 0; t < T - 1; ++t) {
    // Q = ht @ W1q.T
    if (pre) {
      mfma_gemm5<<<dim3(cdiv(DD, 128), 1, 19), 256, 0, stream>>>(
          ht_hi, ht_lo, wq_h, wq_l, DDP, PBUF, B, DD, 96);
    } else {
      mfma_gemm4<<<dim3(cdiv(DD, 128), 1, 15), 256, 0, stream>>>(
          ht_hi, ht_lo, DDP, attn_W1, DD + DENC, DD, attn_W1, DD + DENC,
          PBUF, B, DD, DD, 120);
    }
    reduce_k<0><<<cdiv(B * DD / 4, 256), 256, 0, stream>>>(
        PBUF, zq, B * DD / 4, (size_t)B * DD, DD, nullptr, Q);
    attn_u_kernel<<<dim3(S, B), 256, 0, stream>>>(Q, Hproj, attn_w2, attn_b2, u);
    softmax_ctx_pack<<<dim3(B, 4), 256, 0, stream>>>(u, h, ht, beta_w, beta_b, emb,
        E + (size_t)t * B, tok, xc_hi, xc_lo, c2_hi, c2_lo);
    // gates = xcat @ [W_ih | W_hh].T  (z=8)
    if (pre) {
      mfma_gemm5<<<dim3(cdiv(G4, 128), 1, 8), 256, 0, stream>>>(
          xc_hi, xc_lo, wg_h, wg_l, KCP, PBUF, B, G4, 384);
    } else {
      mfma_gemm4<<<dim3(cdiv(G4, 128), 1, 8), 256, 0, stream>>>(
          xc_hi, xc_lo, KCP, W_ih, DE + DENC, DE + DENC, W_hh, DD,
          PBUF, B, G4, KC, 384);
    }
    lstm_fused<<<cdiv(B * DD, 256), 256, 0, stream>>>(
        PBUF, 8, b_ih, b_hh, ct, ht, c2_hi, c2_lo, ht_hi, ht_lo);
    // logits = cat2 @ out_W.T  (z=10) -> d_out[t]
    float* logits_t = out + (size_t)t * B * V;
    if (pre) {
      mfma_gemm5<<<dim3(cdiv(V, 128), 1, 10), 256, 0, stream>>>(
          c2_hi, c2_lo, ow_h, ow_l, KCP, PBUF, B, V, 288);
    } else {
      mfma_gemm4<<<dim3(cdiv(V, 128), 1, 10), 256, 0, stream>>>(
          c2_hi, c2_lo, KCP, out_W, KC, KC, out_W, KC,
          PBUF, B, V, KC, 288);
    }
    reduce_k<0><<<cdiv(B * V / 4, 256), 256, 0, stream>>>(
        PBUF, 10, B * V / 4, (size_t)B * V, V, out_b, logits_t);
    argmax_kernel<<<B, 256, 0, stream>>>(logits_t, tok);
  }
  (void)in_sizes; (void)n_in; (void)out_size; (void)ws_size;
}